// Round 17
// baseline (242.542 us; speedup 1.0000x reference)
//
#include <hip/hip_runtime.h>
#include <hip/hip_bf16.h>
#include <stdint.h>

// Problem constants
#define BB   2
#define CIN  32
#define COUT 16
#define DD   48
#define HIN  64
#define WIN  128
#define H2   128
#define W2   256

// Padded i8 activation tensor geometry (1 site = 32 i8 = 32 B)
#define WP   258
#define HP   130
#define PDP  (WP * HP)           // 33540 sites per plane
#define PB   (PDP * 50)          // batch stride (48 planes + 2 pad)
#define NSITES ((size_t)PB * BB)

#define NPAD_R1 134160
#define NPAD_R2 49536
#define NPAD_R3 24576
#define NPAD   (NPAD_R1 + NPAD_R2 + NPAD_R3)

typedef int v4i __attribute__((ext_vector_type(4)));

// ---------------------------------------------------------------------------
// prepB (verified round 16): blocks 0..15 build B-matrix + BN constants;
// blocks >=16 zero the pad sites of xb.
// ---------------------------------------------------------------------------
__global__ __launch_bounds__(256) void ibc3d_prepB(
    const float* __restrict__ wgt, const float* __restrict__ gamma,
    const float* __restrict__ beta, const float* __restrict__ rmean,
    const float* __restrict__ rvar, uint8_t* __restrict__ Bmat,
    float* __restrict__ scale, float* __restrict__ shift,
    uint8_t* __restrict__ xb)
{
    __shared__ double sp[256];
    int bid = blockIdx.x, tid = threadIdx.x;

    if (bid < 16) {
        int co = bid;
        const float* wsl = wgt + (size_t)co * (CIN * 27);

        if (tid < 56) {
            int p  = tid >> 2;
            int lq = tid & 3;
            int l  = lq * 16 + co;
            int tap = (l >= 32) ? (2 * p + 1) : (2 * p);
            uint32_t dw[4] = {0u, 0u, 0u, 0u};
            if (tap < 27) {
                int cib = ((l >> 4) & 1) * 16;
                for (int jj = 0; jj < 16; ++jj) {
                    float w = wsl[(cib + jj) * 27 + tap];
                    uint32_t sb = w > 0.f ? 0x01u : (w < 0.f ? 0xFFu : 0x00u);
                    dw[jj >> 2] |= sb << ((jj & 3) * 8);
                }
            }
            *(uint4*)(Bmat + ((size_t)p * 64 + l) * 16) =
                make_uint4(dw[0], dw[1], dw[2], dw[3]);
        }

        double s = 0.0;
        for (int i = tid; i < CIN * 27; i += 256) s += fabs((double)wsl[i]);
        sp[tid] = s;
        __syncthreads();
#pragma unroll
        for (int st = 128; st > 0; st >>= 1) {
            if (tid < st) sp[tid] += sp[tid + st];
            __syncthreads();
        }
        if (tid == 0) {
            float alpha = (float)(sp[0] / (double)(CIN * 27));
            float inv = gamma[co] / sqrtf(rvar[co] + 1e-5f);
            scale[co] = alpha * inv;
            shift[co] = beta[co] - rmean[co] * inv;
        }
    } else {
        int i = (bid - 16) * 256 + tid;
        if (i >= NPAD) return;
        size_t site;
        if (i < NPAD_R1) {
            int bq = i / 67080; int m = i - bq * 67080;
            int ds = m / PDP;   int r2 = m - ds * PDP;
            int hp = r2 / WP,   wp = r2 % WP;
            site = (size_t)bq * PB + (size_t)(ds ? 49 : 0) * PDP + hp * WP + wp;
        } else if (i < NPAD_R1 + NPAD_R2) {
            int i2 = i - NPAD_R1;
            int bq = i2 / 24768; int m = i2 - bq * 24768;
            int dp = 1 + m / 516; int r2 = m - (dp - 1) * 516;
            int hp = (r2 / WP) ? 129 : 0; int wp = r2 % WP;
            site = (size_t)bq * PB + (size_t)dp * PDP + hp * WP + wp;
        } else {
            int i3 = i - NPAD_R1 - NPAD_R2;
            int bq = i3 / 12288; int m = i3 - bq * 12288;
            int dp = 1 + m / 256; int r2 = m & 255;
            int hp = 1 + (r2 >> 1); int wp = (r2 & 1) ? 257 : 0;
            site = (size_t)bq * PB + (size_t)dp * PDP + hp * WP + wp;
        }
        uint8_t* pz = xb + site * 32;
        *(uint4*)pz        = make_uint4(0u, 0u, 0u, 0u);
        *(uint4*)(pz + 16) = make_uint4(0u, 0u, 0u, 0u);
    }
}

// ---------------------------------------------------------------------------
// packi8 (verified round 16): upsample + sign-pack to +1/-1 i8 padded tensor.
// ---------------------------------------------------------------------------
__global__ __launch_bounds__(256) void ibc3d_packi8(
    const float* __restrict__ x, uint8_t* __restrict__ xb)
{
    int idx = blockIdx.x * 256 + threadIdx.x;
    int j  = idx & 31;
    int q  = (idx >> 5) & 3;
    int h2 = (idx >> 7) & 127;
    int pl = idx >> 14;
    int d = pl % DD, b = pl / DD;

    int m = h2 >> 1, qq = h2 & 1;
    int rT = qq ? m : (m > 0 ? m - 1 : 0);
    int rB = qq ? (m < HIN - 1 ? m + 1 : HIN - 1) : m;
    float wT = qq ? 0.75f : 0.25f;
    float wB = 1.0f - wT;

    int c0 = 4 * j;
    int cl = c0 >= 2 ? c0 - 2 : 0;
    int cr = (c0 + 4 <= WIN - 2) ? c0 + 4 : WIN - 2;

    const float* xp = x + ((size_t)b * CIN * DD + d) * (HIN * WIN);
    int oT = rT * WIN, oB2 = rB * WIN;

    uint32_t d0[8], d1[8];
#pragma unroll
    for (int k = 0; k < 8; ++k) { d0[k] = 0u; d1[k] = 0u; }

    for (int c = 0; c < 8; ++c) {
        int ci = q * 8 + c;
        const float* xc = xp + (size_t)ci * (DD * HIN * WIN);
        float cT[6], cB[6];
        {
            const float* rowT = xc + oT;
            float2 L = *(const float2*)(rowT + cl);
            float4 M = *(const float4*)(rowT + c0);
            float2 R = *(const float2*)(rowT + cr);
            cT[0] = (j > 0)  ? L.y : L.x;
            cT[1] = M.x; cT[2] = M.y; cT[3] = M.z; cT[4] = M.w;
            cT[5] = (j < 31) ? R.x : R.y;
        }
        {
            const float* rowB = xc + oB2;
            float2 L = *(const float2*)(rowB + cl);
            float4 M = *(const float4*)(rowB + c0);
            float2 R = *(const float2*)(rowB + cr);
            cB[0] = (j > 0)  ? L.y : L.x;
            cB[1] = M.x; cB[2] = M.y; cB[3] = M.z; cB[4] = M.w;
            cB[5] = (j < 31) ? R.x : R.y;
        }

        float v[8];
#pragma unroll
        for (int t = 0; t < 4; ++t) {
            float uT0 = 0.25f * cT[t]     + 0.75f * cT[t + 1];
            float uT1 = 0.75f * cT[t + 1] + 0.25f * cT[t + 2];
            float uB0 = 0.25f * cB[t]     + 0.75f * cB[t + 1];
            float uB1 = 0.75f * cB[t + 1] + 0.25f * cB[t + 2];
            v[2 * t]     = wT * uT0 + wB * uB0;
            v[2 * t + 1] = wT * uT1 + wB * uB1;
        }

        float amin = 3.4e38f;
#pragma unroll
        for (int k = 0; k < 8; ++k) amin = fminf(amin, fabsf(v[k]));

        uint32_t sb[8];
        if (__builtin_expect(amin < 1e-5f, 0)) {
            double dwT = (double)wT, dwB = 1.0 - (double)wT;
#pragma unroll
            for (int t = 0; t < 4; ++t) {
                double eT0 = 0.25 * (double)cT[t]     + 0.75 * (double)cT[t + 1];
                double eT1 = 0.75 * (double)cT[t + 1] + 0.25 * (double)cT[t + 2];
                double eB0 = 0.25 * (double)cB[t]     + 0.75 * (double)cB[t + 1];
                double eB1 = 0.75 * (double)cB[t + 1] + 0.25 * (double)cB[t + 2];
                sb[2 * t]     = (dwT * eT0 + dwB * eB0) >= 0.0 ? 0x01u : 0xFFu;
                sb[2 * t + 1] = (dwT * eT1 + dwB * eB1) >= 0.0 ? 0x01u : 0xFFu;
            }
        } else {
#pragma unroll
            for (int k = 0; k < 8; ++k) sb[k] = v[k] >= 0.f ? 0x01u : 0xFFu;
        }

        if (c < 4) {
#pragma unroll
            for (int k = 0; k < 8; ++k) d0[k] |= sb[k] << (c * 8);
        } else {
#pragma unroll
            for (int k = 0; k < 8; ++k) d1[k] |= sb[k] << ((c - 4) * 8);
        }
    }

    size_t base = (size_t)b * PB + (size_t)(d + 1) * PDP +
                  (size_t)(h2 + 1) * WP + 1 + j * 8;
#pragma unroll
    for (int k = 0; k < 8; ++k)
        *(uint2*)(xb + (base + k) * 32 + q * 8) = make_uint2(d0[k], d1[k]);
}

// ---------------------------------------------------------------------------
// convmf2: same math/indexing as the refcheck-verified convmf, but:
//  - __launch_bounds__(256,2) so the compiler keeps bf0..bf13 RESIDENT
//    (round-16's VGPR=44 proved it rematerialized them -> load-bound);
//  - named scalars only (no arrays -> no scratch);
//  - A triple-buffered, loads issued 2 tap-pairs ahead (8 loads in flight).
// ---------------------------------------------------------------------------
#define LOADP(N, p_)                                                          \
    { const int t0_ = 2 * (p_);                                               \
      const int t1_ = (2 * (p_) + 1 < 27) ? (2 * (p_) + 1) : 26;              \
      const int o0_ = ((t0_ / 9 - 1) * PDP + ((t0_ % 9) / 3 - 1) * WP + (t0_ % 3 - 1)) * 32; \
      const int o1_ = ((t1_ / 9 - 1) * PDP + ((t1_ % 9) / 3 - 1) * WP + (t1_ % 3 - 1)) * 32; \
      const int ob_ = hi ? o1_ : o0_;                                         \
      N##0 = *(const v4i*)(P0 + ob_); N##1 = *(const v4i*)(P1 + ob_);         \
      N##2 = *(const v4i*)(P2 + ob_); N##3 = *(const v4i*)(P3 + ob_); }

#define STEP(p_, CUR, NX2)                                                    \
    { if ((p_) + 2 < 14) { LOADP(NX2, (p_) + 2); }                            \
      acc0 = __builtin_amdgcn_mfma_i32_16x16x64_i8(CUR##0, bf##p_, acc0, 0, 0, 0); \
      acc1 = __builtin_amdgcn_mfma_i32_16x16x64_i8(CUR##1, bf##p_, acc1, 0, 0, 0); \
      acc2 = __builtin_amdgcn_mfma_i32_16x16x64_i8(CUR##2, bf##p_, acc2, 0, 0, 0); \
      acc3 = __builtin_amdgcn_mfma_i32_16x16x64_i8(CUR##3, bf##p_, acc3, 0, 0, 0); }

__global__ __launch_bounds__(256, 2) void ibc3d_convmf2(
    const uint8_t* __restrict__ xb, const uint8_t* __restrict__ Bmat,
    const float* __restrict__ scaleg, const float* __restrict__ shiftg,
    float* __restrict__ out)
{
    int bid = blockIdx.x;            // 96*128
    int h2 = bid & 127;
    int pl = bid >> 7;
    int b = pl / DD, d = pl % DD;
    int tid = threadIdx.x;
    int l = tid & 63, wid = tid >> 6;
    int ls = l & 15;
    bool hi = l >= 32;
    int ci0 = ((l >> 4) & 1) * 16;

    v4i bf0  = *(const v4i*)(Bmat + ((size_t)0  * 64 + l) * 16);
    v4i bf1  = *(const v4i*)(Bmat + ((size_t)1  * 64 + l) * 16);
    v4i bf2  = *(const v4i*)(Bmat + ((size_t)2  * 64 + l) * 16);
    v4i bf3  = *(const v4i*)(Bmat + ((size_t)3  * 64 + l) * 16);
    v4i bf4  = *(const v4i*)(Bmat + ((size_t)4  * 64 + l) * 16);
    v4i bf5  = *(const v4i*)(Bmat + ((size_t)5  * 64 + l) * 16);
    v4i bf6  = *(const v4i*)(Bmat + ((size_t)6  * 64 + l) * 16);
    v4i bf7  = *(const v4i*)(Bmat + ((size_t)7  * 64 + l) * 16);
    v4i bf8  = *(const v4i*)(Bmat + ((size_t)8  * 64 + l) * 16);
    v4i bf9  = *(const v4i*)(Bmat + ((size_t)9  * 64 + l) * 16);
    v4i bf10 = *(const v4i*)(Bmat + ((size_t)10 * 64 + l) * 16);
    v4i bf11 = *(const v4i*)(Bmat + ((size_t)11 * 64 + l) * 16);
    v4i bf12 = *(const v4i*)(Bmat + ((size_t)12 * 64 + l) * 16);
    v4i bf13 = *(const v4i*)(Bmat + ((size_t)13 * 64 + l) * 16);

    size_t base = (size_t)b * PB + (size_t)(d + 1) * PDP +
                  (size_t)(h2 + 1) * WP + 1;
    const uint8_t* P0 = xb + (base + (size_t)((wid * 4 + 0) * 16 + ls)) * 32 + ci0;
    const uint8_t* P1 = xb + (base + (size_t)((wid * 4 + 1) * 16 + ls)) * 32 + ci0;
    const uint8_t* P2 = xb + (base + (size_t)((wid * 4 + 2) * 16 + ls)) * 32 + ci0;
    const uint8_t* P3 = xb + (base + (size_t)((wid * 4 + 3) * 16 + ls)) * 32 + ci0;

    v4i AA0, AA1, AA2, AA3, AB0, AB1, AB2, AB3, AC0, AC1, AC2, AC3;
    v4i acc0 = (v4i){0, 0, 0, 0}, acc1 = (v4i){0, 0, 0, 0};
    v4i acc2 = (v4i){0, 0, 0, 0}, acc3 = (v4i){0, 0, 0, 0};

    LOADP(AA, 0)
    LOADP(AB, 1)
    STEP(0,  AA, AC)
    STEP(1,  AB, AA)
    STEP(2,  AC, AB)
    STEP(3,  AA, AC)
    STEP(4,  AB, AA)
    STEP(5,  AC, AB)
    STEP(6,  AA, AC)
    STEP(7,  AB, AA)
    STEP(8,  AC, AB)
    STEP(9,  AA, AC)
    STEP(10, AB, AA)
    STEP(11, AC, AB)
    STEP(12, AA, AC)
    STEP(13, AB, AC)

    int co = ls;
    float sc = scaleg[co], sh = shiftg[co];
    size_t obase = (((size_t)(b * COUT + co) * DD + d) * H2 + h2) * W2;
    int rb = (l >> 4) << 2;
#pragma unroll
    for (int r = 0; r < 4; ++r) {
        float y = (float)acc0[r] * sc + sh;
        out[obase + (wid * 4 + 0) * 16 + rb + r] = y > 0.f ? y : 0.f;
    }
#pragma unroll
    for (int r = 0; r < 4; ++r) {
        float y = (float)acc1[r] * sc + sh;
        out[obase + (wid * 4 + 1) * 16 + rb + r] = y > 0.f ? y : 0.f;
    }
#pragma unroll
    for (int r = 0; r < 4; ++r) {
        float y = (float)acc2[r] * sc + sh;
        out[obase + (wid * 4 + 2) * 16 + rb + r] = y > 0.f ? y : 0.f;
    }
#pragma unroll
    for (int r = 0; r < 4; ++r) {
        float y = (float)acc3[r] * sc + sh;
        out[obase + (wid * 4 + 3) * 16 + rb + r] = y > 0.f ? y : 0.f;
    }
}

// ---------------------------------------------------------------------------
// fused zero-scratch fallback (unchanged from passing rounds).
// ---------------------------------------------------------------------------
__device__ __forceinline__ uint32_t pack_word(const float* __restrict__ x,
                                              int b, int d, int h2, int w2)
{
    int m = h2 >> 1, dh = h2 & 1;
    int n = w2 >> 1, dwp = w2 & 1;
    int rA = m + dh - 1;
    int rB = rA + 1;
    double wA = dh ? 0.75 : 0.25;
    double wB = 1.0 - wA;
    rA = rA < 0 ? 0 : rA;
    rB = rB > (HIN - 1) ? (HIN - 1) : rB;
    int cA = n + dwp - 1;
    int cB = cA + 1;
    double wC = dwp ? 0.75 : 0.25;
    double wD = 1.0 - wC;
    cA = cA < 0 ? 0 : cA;
    cB = cB > (WIN - 1) ? (WIN - 1) : cB;

    const float* xp = x + ((size_t)b * CIN * DD + d) * (HIN * WIN);
    int oA = rA * WIN, oB = rB * WIN;
    uint32_t word = 0;
    for (int ci = 0; ci < CIN; ++ci) {
        const float* xc = xp + (size_t)ci * (DD * HIN * WIN);
        float a0 = xc[oA + cA], a1 = xc[oA + cB];
        float b0 = xc[oB + cA], b1 = xc[oB + cB];
        double t0 = wA * (double)a0 + wB * (double)b0;
        double t1 = wA * (double)a1 + wB * (double)b1;
        double v  = wC * t0 + wD * t1;
        word |= (v >= 0.0 ? 1u : 0u) << ci;
    }
    return word;
}

__global__ __launch_bounds__(256) void ibc3d_fused(
    const float* __restrict__ x, const float* __restrict__ wgt,
    const float* __restrict__ gamma, const float* __restrict__ beta,
    const float* __restrict__ rmean, const float* __restrict__ rvar,
    float* __restrict__ out)
{
    __shared__ uint32_t sbw[27 * 16];
    __shared__ float sscale[16];
    __shared__ float sshift[16];
    __shared__ uint32_t sw[3][10][264];

    int tid = threadIdx.x;
    for (int t = tid; t < 27 * 16; t += 256) {
        int tap = t >> 4, co = t & 15;
        uint32_t word = 0;
        for (int ci = 0; ci < CIN; ++ci) {
            float v = wgt[(co * CIN + ci) * 27 + tap];
            word |= (v > 0.0f ? 1u : 0u) << ci;
        }
        sbw[t] = word;
    }
    if (tid < 16) {
        int co = tid;
        double s = 0.0;
        for (int i = 0; i < CIN * 27; ++i)
            s += fabs((double)wgt[co * CIN * 27 + i]);
        float alpha = (float)(s / (double)(CIN * 27));
        float inv = gamma[co] / sqrtf(rvar[co] + 1e-5f);
        sscale[co] = alpha * inv;
        sshift[co] = beta[co] - rmean[co] * inv;
    }

    int bid = blockIdx.x;
    int hq  = bid & 15;
    int r   = bid >> 4;
    int b   = r / DD;
    int d   = r % DD;
    int h2base = hq * 8;

    for (int i = tid; i < 3 * 10 * 258; i += 256) {
        int kd  = i / 2580;
        int rem = i - kd * 2580;
        int ri  = rem / 258;
        int ciw = rem - ri * 258;
        int dd = d + kd - 1;
        int h2 = h2base - 1 + ri;
        int w2 = ciw - 1;
        uint32_t word = 0;
        if (dd >= 0 && dd < DD && h2 >= 0 && h2 < H2 && w2 >= 0 && w2 < W2)
            word = pack_word(x, b, dd, h2, w2);
        sw[kd][ri][ciw] = word;
    }
    __syncthreads();

    int w2 = tid;
    for (int p = 0; p < 8; ++p) {
        int h2 = h2base + p;
        int acc[16];
#pragma unroll
        for (int c = 0; c < 16; ++c) acc[c] = 0;
        int nv = 0;
        for (int kd = 0; kd < 3; ++kd) {
            int dd = d + kd - 1;
            if (dd < 0 || dd >= DD) continue;
            for (int kh = 0; kh < 3; ++kh) {
                int hh = h2 + kh - 1;
                if (hh < 0 || hh >= H2) continue;
                for (int kw = 0; kw < 3; ++kw) {
                    int ww = w2 + kw - 1;
                    if (ww < 0 || ww >= W2) continue;
                    uint32_t word = sw[kd][p + kh][w2 + kw];
                    nv += 1;
                    int tap = kd * 9 + kh * 3 + kw;
#pragma unroll
                    for (int co = 0; co < 16; ++co)
                        acc[co] += __popc(word ^ sbw[tap * 16 + co]);
                }
            }
        }
        float base = 32.0f * (float)nv;
#pragma unroll
        for (int co = 0; co < 16; ++co) {
            float y = (base - 2.0f * (float)acc[co]) * sscale[co] + sshift[co];
            y = y > 0.0f ? y : 0.0f;
            size_t oidx = (((size_t)(b * COUT + co) * DD + d) * H2 + h2) * W2 + w2;
            out[oidx] = y;
        }
    }
}

extern "C" void kernel_launch(void* const* d_in, const int* in_sizes, int n_in,
                              void* d_out, int out_size, void* d_ws, size_t ws_size,
                              hipStream_t stream)
{
    (void)in_sizes; (void)n_in; (void)out_size;
    const float* x     = (const float*)d_in[0];
    const float* wgt   = (const float*)d_in[1];
    const float* gamma = (const float*)d_in[2];
    const float* beta  = (const float*)d_in[3];
    const float* rmean = (const float*)d_in[4];
    const float* rvar  = (const float*)d_in[5];
    float* out = (float*)d_out;

    const size_t XBOFF = 32768;
    const size_t need = XBOFF + NSITES * 32;   // ~107.4 MB

    if (d_ws != nullptr && ws_size >= need) {
        uint8_t* ws    = (uint8_t*)d_ws;
        uint8_t* Bmat  = ws;
        float*   scale = (float*)(ws + 16384);
        float*   shift = (float*)(ws + 16448);
        uint8_t* xb    = ws + XBOFF;

        int zblocks = 16 + (NPAD + 255) / 256;
        ibc3d_prepB<<<zblocks, 256, 0, stream>>>(wgt, gamma, beta, rmean, rvar,
                                                 Bmat, scale, shift, xb);
        ibc3d_packi8<<<6144, 256, 0, stream>>>(x, xb);
        ibc3d_convmf2<<<BB * DD * H2, 256, 0, stream>>>(xb, Bmat, scale, shift, out);
    } else {
        ibc3d_fused<<<BB * DD * (H2 / 8), 256, 0, stream>>>(
            x, wgt, gamma, beta, rmean, rvar, out);
    }
}

// Round 18
// 181.627 us; speedup vs baseline: 1.3354x; 1.3354x over previous
//
#include <hip/hip_runtime.h>
#include <hip/hip_bf16.h>
#include <stdint.h>

// Problem constants
#define BB   2
#define CIN  32
#define COUT 16
#define DD   48
#define HIN  64
#define WIN  128
#define H2   128
#define W2   256

// Padded bit-packed tensor: word = 32 ci sign bits per site.
// Padded cols: 264 (cols 3..260 hold w2=-1..256; left pad 0..2 unused, keeps
// uint4 stores 16B-aligned). Padded rows: 130 (row h2+1). Padded planes: 50
// per batch (plane d+1). All pads zero; conv reads unconditionally.
#define W2P  264
#define HPR  130
#define PDPW (HPR * W2P)          // 34320 words per plane
#define PBW  (50 * PDPW)          // 1,716,000 words per batch
#define TOTW (2 * PBW)            // 3,432,000 words = 13.73 MB

// ---------------------------------------------------------------------------
// prep2 (1 block x 512): weight sign words bw[tap*16+co]; alpha via 32-lane
// shfl reduce; edge-class tables: A2[co] = -2*scale, Bc[class*16+co] =
// (32*nv + 2*corr)*scale + shift, where corr = sum_{invalid taps} popc(bw).
// ---------------------------------------------------------------------------
__global__ __launch_bounds__(512) void ibc3d_prep2(
    const float* __restrict__ wgt, const float* __restrict__ gamma,
    const float* __restrict__ beta, const float* __restrict__ rmean,
    const float* __restrict__ rvar, uint32_t* __restrict__ bwg,
    float* __restrict__ A2g, float* __restrict__ Bcg)
{
    __shared__ uint32_t sbw[432];
    __shared__ float ssc[16], ssh[16];
    int t = threadIdx.x;

    if (t < 432) {
        int tap = t >> 4, co = t & 15;
        uint32_t word = 0;
        for (int ci = 0; ci < CIN; ++ci) {
            float v = wgt[(co * CIN + ci) * 27 + tap];
            word |= (v > 0.0f ? 1u : 0u) << ci;
        }
        sbw[t] = word;
        bwg[t] = word;
    }
    {
        int co = t >> 5, lane = t & 31;
        double p = 0.0;
        for (int k = 0; k < 27; ++k)
            p += fabs((double)wgt[co * (CIN * 27) + lane + 32 * k]);
#pragma unroll
        for (int s = 16; s >= 1; s >>= 1) p += __shfl_down(p, s, 32);
        if (lane == 0) {
            float alpha = (float)(p / (double)(CIN * 27));
            float inv = gamma[co] / sqrtf(rvar[co] + 1e-5f);
            ssc[co] = alpha * inv;
            ssh[co] = beta[co] - rmean[co] * inv;
        }
    }
    __syncthreads();
    if (t < 16) A2g[t] = -2.0f * ssc[t];
    if (t < 432) {
        int cls = t >> 4, co = t & 15;
        int cd = cls / 9, ch = (cls / 3) % 3, cw = cls % 3;
        int corr = 0, nv = 0;
        for (int tap = 0; tap < 27; ++tap) {
            int kd = tap / 9, kh = (tap / 3) % 3, kw = tap % 3;
            bool inval = (cd == 0 && kd == 0) || (cd == 2 && kd == 2) ||
                         (ch == 0 && kh == 0) || (ch == 2 && kh == 2) ||
                         (cw == 0 && kw == 0) || (cw == 2 && kw == 2);
            if (inval) corr += __popc(sbw[tap * 16 + co]);
            else ++nv;
        }
        Bcg[t] = (32.0f * (float)nv + 2.0f * (float)corr) * ssc[co] + ssh[co];
    }
}

// ---------------------------------------------------------------------------
// zerop: zero the whole padded bx (pads stay 0; pack overwrites interior).
// ---------------------------------------------------------------------------
__global__ __launch_bounds__(256) void ibc3d_zerop(uint32_t* __restrict__ bxp)
{
    int idx = blockIdx.x * 256 + threadIdx.x;
    if (idx < TOTW / 4)
        ((uint4*)bxp)[idx] = make_uint4(0u, 0u, 0u, 0u);
}

// ---------------------------------------------------------------------------
// packp8: packr8 (measured winner) with stores retargeted to the padded
// layout. One thread packs 1 output row x 8 cols; fp32 interp with fp64
// fallback when any |v| < 1e-5.
// ---------------------------------------------------------------------------
__global__ __launch_bounds__(256) void ibc3d_packp8(
    const float* __restrict__ x, uint32_t* __restrict__ bxp)
{
    int per = gridDim.x >> 3;
    int bid = (blockIdx.x & 7) * per + (blockIdx.x >> 3);
    int idx = bid * 256 + threadIdx.x;   // [0, 96*4096)
    int j  = idx & 31;               // 8-col group [0,32)
    int h2 = (idx >> 5) & (H2 - 1);  // output row [0,128)
    int pl = idx >> 12;              // plane [0,96)
    int d  = pl % DD;
    int b  = pl / DD;

    int m = h2 >> 1, q = h2 & 1;
    int rT = q ? m : (m > 0 ? m - 1 : 0);
    int rB = q ? (m < HIN - 1 ? m + 1 : HIN - 1) : m;
    float wT = q ? 0.75f : 0.25f;
    float wB = 1.0f - wT;

    int c0 = 4 * j;
    int cl = c0 >= 2 ? c0 - 2 : 0;
    int cr = (c0 + 4 <= WIN - 2) ? c0 + 4 : WIN - 2;

    const float* xp = x + ((size_t)b * CIN * DD + d) * (HIN * WIN);
    int oT = rT * WIN, oB2 = rB * WIN;

    uint32_t w[8];
#pragma unroll
    for (int k = 0; k < 8; ++k) w[k] = 0u;

#pragma unroll 2
    for (int ci = 0; ci < CIN; ++ci) {
        const float* xc = xp + (size_t)ci * (DD * HIN * WIN);
        float cT[6], cB[6];
        {
            const float* rowT = xc + oT;
            float2 L = *(const float2*)(rowT + cl);
            float4 M = *(const float4*)(rowT + c0);
            float2 R = *(const float2*)(rowT + cr);
            cT[0] = (j > 0)  ? L.y : L.x;
            cT[1] = M.x; cT[2] = M.y; cT[3] = M.z; cT[4] = M.w;
            cT[5] = (j < 31) ? R.x : R.y;
        }
        {
            const float* rowB = xc + oB2;
            float2 L = *(const float2*)(rowB + cl);
            float4 M = *(const float4*)(rowB + c0);
            float2 R = *(const float2*)(rowB + cr);
            cB[0] = (j > 0)  ? L.y : L.x;
            cB[1] = M.x; cB[2] = M.y; cB[3] = M.z; cB[4] = M.w;
            cB[5] = (j < 31) ? R.x : R.y;
        }

        float v[8];
#pragma unroll
        for (int t = 0; t < 4; ++t) {
            float uT0 = 0.25f * cT[t]     + 0.75f * cT[t + 1];
            float uT1 = 0.75f * cT[t + 1] + 0.25f * cT[t + 2];
            float uB0 = 0.25f * cB[t]     + 0.75f * cB[t + 1];
            float uB1 = 0.75f * cB[t + 1] + 0.25f * cB[t + 2];
            v[2 * t]     = wT * uT0 + wB * uB0;
            v[2 * t + 1] = wT * uT1 + wB * uB1;
        }

        float amin = 3.4e38f;
#pragma unroll
        for (int k = 0; k < 8; ++k)
            amin = fminf(amin, fabsf(v[k]));

        if (__builtin_expect(amin < 1e-5f, 0)) {
            double dwT = (double)wT, dwB = 1.0 - (double)wT;
#pragma unroll
            for (int t = 0; t < 4; ++t) {
                double eT0 = 0.25 * (double)cT[t]     + 0.75 * (double)cT[t + 1];
                double eT1 = 0.75 * (double)cT[t + 1] + 0.25 * (double)cT[t + 2];
                double eB0 = 0.25 * (double)cB[t]     + 0.75 * (double)cB[t + 1];
                double eB1 = 0.75 * (double)cB[t + 1] + 0.25 * (double)cB[t + 2];
                uint32_t s0 = (dwT * eT0 + dwB * eB0) >= 0.0;
                uint32_t s1 = (dwT * eT1 + dwB * eB1) >= 0.0;
                w[2 * t]     |= s0 << ci;
                w[2 * t + 1] |= s1 << ci;
            }
        } else {
#pragma unroll
            for (int k = 0; k < 8; ++k)
                w[k] |= (v[k] >= 0.0f ? 1u : 0u) << ci;
        }
    }

    // padded store: plane d+1, row h2+1, cols (w2 + 4) with w2 = 8j
    size_t base = ((size_t)((b * 50 + d + 1) * HPR + (h2 + 1))) * W2P + 4 + 8 * j;
    *(uint4*)(bxp + base)     = make_uint4(w[0], w[1], w[2], w[3]);
    *(uint4*)(bxp + base + 4) = make_uint4(w[4], w[5], w[6], w[7]);
}

// ---------------------------------------------------------------------------
// convp: branchless popcount conv over the zero-padded bx. 3 plane-base
// pointers; 27 loads with immediate offsets (kh*1056 + kw*4 bytes); 864
// xor+bcnt; epilogue y = relu(fma(A2[co], acc, Bc[class*16+co])). Padding
// contamination is exactly cancelled by the Bc table (corr term).
// ---------------------------------------------------------------------------
__global__ __launch_bounds__(256) void ibc3d_convp(
    const uint32_t* __restrict__ bxp, const uint32_t* __restrict__ bwg,
    const float* __restrict__ A2g, const float* __restrict__ Bcg,
    float* __restrict__ out)
{
    int bid   = blockIdx.x;          // plane*128 + h2
    int h2    = bid & (H2 - 1);
    int plane = bid >> 7;
    int d     = plane % DD;
    int b     = plane / DD;
    int w2    = threadIdx.x;

    // kd=0 base: padded plane (b*50 + d), padded row h2, padded col w2+3
    const uint32_t* P0 = bxp +
        ((size_t)((b * 50 + d) * HPR + h2)) * W2P + w2 + 3;

    int acc[16];
#pragma unroll
    for (int c = 0; c < 16; ++c) acc[c] = 0;

#pragma unroll
    for (int kd = 0; kd < 3; ++kd) {
        const uint32_t* P = P0 + kd * PDPW;
#pragma unroll
        for (int kh = 0; kh < 3; ++kh) {
#pragma unroll
            for (int kw = 0; kw < 3; ++kw) {
                uint32_t word = P[kh * W2P + kw];
                int tap = kd * 9 + kh * 3 + kw;
#pragma unroll
                for (int co = 0; co < 16; ++co)
                    acc[co] += __popc(word ^ bwg[tap * 16 + co]);
            }
        }
    }

    int cd = (d == 0)  ? 0 : ((d == DD - 1) ? 2 : 1);
    int ch = (h2 == 0) ? 0 : ((h2 == H2 - 1) ? 2 : 1);
    int cw = (w2 == 0) ? 0 : ((w2 == W2 - 1) ? 2 : 1);
    int cls16 = (cd * 9 + ch * 3 + cw) * 16;

    size_t obase = (((size_t)(b * COUT) * DD + d) * H2 + h2) * W2 + w2;
#pragma unroll
    for (int co = 0; co < 16; ++co) {
        float y = fmaf(A2g[co], (float)acc[co], Bcg[cls16 + co]);
        y = y > 0.0f ? y : 0.0f;
        out[obase + (size_t)co * (DD * H2 * W2)] = y;
    }
}

// ---------------------------------------------------------------------------
// fused zero-scratch fallback (unchanged from passing rounds).
// ---------------------------------------------------------------------------
__device__ __forceinline__ uint32_t pack_word(const float* __restrict__ x,
                                              int b, int d, int h2, int w2)
{
    int m = h2 >> 1, dh = h2 & 1;
    int n = w2 >> 1, dwp = w2 & 1;
    int rA = m + dh - 1;
    int rB = rA + 1;
    double wA = dh ? 0.75 : 0.25;
    double wB = 1.0 - wA;
    rA = rA < 0 ? 0 : rA;
    rB = rB > (HIN - 1) ? (HIN - 1) : rB;
    int cA = n + dwp - 1;
    int cB = cA + 1;
    double wC = dwp ? 0.75 : 0.25;
    double wD = 1.0 - wC;
    cA = cA < 0 ? 0 : cA;
    cB = cB > (WIN - 1) ? (WIN - 1) : cB;

    const float* xp = x + ((size_t)b * CIN * DD + d) * (HIN * WIN);
    int oA = rA * WIN, oB = rB * WIN;
    uint32_t word = 0;
    for (int ci = 0; ci < CIN; ++ci) {
        const float* xc = xp + (size_t)ci * (DD * HIN * WIN);
        float a0 = xc[oA + cA], a1 = xc[oA + cB];
        float b0 = xc[oB + cA], b1 = xc[oB + cB];
        double t0 = wA * (double)a0 + wB * (double)b0;
        double t1 = wA * (double)a1 + wB * (double)b1;
        double v  = wC * t0 + wD * t1;
        word |= (v >= 0.0 ? 1u : 0u) << ci;
    }
    return word;
}

__global__ __launch_bounds__(256) void ibc3d_fused(
    const float* __restrict__ x, const float* __restrict__ wgt,
    const float* __restrict__ gamma, const float* __restrict__ beta,
    const float* __restrict__ rmean, const float* __restrict__ rvar,
    float* __restrict__ out)
{
    __shared__ uint32_t sbw[27 * 16];
    __shared__ float sscale[16];
    __shared__ float sshift[16];
    __shared__ uint32_t sw[3][10][264];

    int tid = threadIdx.x;
    for (int t = tid; t < 27 * 16; t += 256) {
        int tap = t >> 4, co = t & 15;
        uint32_t word = 0;
        for (int ci = 0; ci < CIN; ++ci) {
            float v = wgt[(co * CIN + ci) * 27 + tap];
            word |= (v > 0.0f ? 1u : 0u) << ci;
        }
        sbw[t] = word;
    }
    if (tid < 16) {
        int co = tid;
        double s = 0.0;
        for (int i = 0; i < CIN * 27; ++i)
            s += fabs((double)wgt[co * CIN * 27 + i]);
        float alpha = (float)(s / (double)(CIN * 27));
        float inv = gamma[co] / sqrtf(rvar[co] + 1e-5f);
        sscale[co] = alpha * inv;
        sshift[co] = beta[co] - rmean[co] * inv;
    }

    int bid = blockIdx.x;
    int hq  = bid & 15;
    int r   = bid >> 4;
    int b   = r / DD;
    int d   = r % DD;
    int h2base = hq * 8;

    for (int i = tid; i < 3 * 10 * 258; i += 256) {
        int kd  = i / 2580;
        int rem = i - kd * 2580;
        int ri  = rem / 258;
        int ciw = rem - ri * 258;
        int dd = d + kd - 1;
        int h2 = h2base - 1 + ri;
        int w2 = ciw - 1;
        uint32_t word = 0;
        if (dd >= 0 && dd < DD && h2 >= 0 && h2 < H2 && w2 >= 0 && w2 < W2)
            word = pack_word(x, b, dd, h2, w2);
        sw[kd][ri][ciw] = word;
    }
    __syncthreads();

    int w2 = tid;
    for (int p = 0; p < 8; ++p) {
        int h2 = h2base + p;
        int acc[16];
#pragma unroll
        for (int c = 0; c < 16; ++c) acc[c] = 0;
        int nv = 0;
        for (int kd = 0; kd < 3; ++kd) {
            int dd = d + kd - 1;
            if (dd < 0 || dd >= DD) continue;
            for (int kh = 0; kh < 3; ++kh) {
                int hh = h2 + kh - 1;
                if (hh < 0 || hh >= H2) continue;
                for (int kw = 0; kw < 3; ++kw) {
                    int ww = w2 + kw - 1;
                    if (ww < 0 || ww >= W2) continue;
                    uint32_t word = sw[kd][p + kh][w2 + kw];
                    nv += 1;
                    int tap = kd * 9 + kh * 3 + kw;
#pragma unroll
                    for (int co = 0; co < 16; ++co)
                        acc[co] += __popc(word ^ sbw[tap * 16 + co]);
                }
            }
        }
        float base = 32.0f * (float)nv;
#pragma unroll
        for (int co = 0; co < 16; ++co) {
            float y = (base - 2.0f * (float)acc[co]) * sscale[co] + sshift[co];
            y = y > 0.0f ? y : 0.0f;
            size_t oidx = (((size_t)(b * COUT + co) * DD + d) * H2 + h2) * W2 + w2;
            out[oidx] = y;
        }
    }
}

extern "C" void kernel_launch(void* const* d_in, const int* in_sizes, int n_in,
                              void* d_out, int out_size, void* d_ws, size_t ws_size,
                              hipStream_t stream)
{
    (void)in_sizes; (void)n_in; (void)out_size;
    const float* x     = (const float*)d_in[0];
    const float* wgt   = (const float*)d_in[1];
    const float* gamma = (const float*)d_in[2];
    const float* beta  = (const float*)d_in[3];
    const float* rmean = (const float*)d_in[4];
    const float* rvar  = (const float*)d_in[5];
    float* out = (float*)d_out;

    const size_t BXOFF = 32768;
    const size_t need = BXOFF + (size_t)TOTW * 4;   // ~13.76 MB

    if (d_ws != nullptr && ws_size >= need) {
        uint8_t*  ws  = (uint8_t*)d_ws;
        uint32_t* bwg = (uint32_t*)ws;              // 1728 B
        float*    A2g = (float*)(ws + 4096);        // 64 B
        float*    Bcg = (float*)(ws + 8192);        // 1728 B
        uint32_t* bxp = (uint32_t*)(ws + BXOFF);    // 13.73 MB

        ibc3d_prep2<<<1, 512, 0, stream>>>(wgt, gamma, beta, rmean, rvar,
                                           bwg, A2g, Bcg);
        ibc3d_zerop<<<(TOTW / 4 + 255) / 256, 256, 0, stream>>>(bxp);
        ibc3d_packp8<<<BB * DD * 16, 256, 0, stream>>>(x, bxp);
        ibc3d_convp<<<BB * DD * H2, 256, 0, stream>>>(bxp, bwg, A2g, Bcg, out);
    } else {
        ibc3d_fused<<<BB * DD * (H2 / 8), 256, 0, stream>>>(
            x, wgt, gamma, beta, rmean, rvar, out);
    }
}